// Round 12
// baseline (898.397 us; speedup 1.0000x reference)
//
#include <hip/hip_runtime.h>
#include <stdint.h>

#define HID    2048
#define MPTS   16425
#define MTILES 129    // ceil(16425/128)
#define NTIL   16     // 2048/128
#define KTIL   64     // 2048/32
#define BIMG   5120   // f16 elems per packed padded B tile image (128 rows * 40)

typedef float    f32x4 __attribute__((ext_vector_type(4)));
typedef _Float16 f16x8 __attribute__((ext_vector_type(8)));

// P-layout (A-operand fragment order) for activations:
// elem(row, k) -> linear ((tile*64+kt)<<12) + rowgrp*512 + quad*128 + lidx*8 + j
//   tile=row>>7, rowgrp=(row>>4)&7, lidx=row&15, kt=k>>5, quad=(k>>3)&3, j=k&7
// Consumer wave A-frag load = base + lane*8 halves (1KB fully coalesced).

// ---------------------------------------------------------------------------
// Pack fp32 W (K x N row-major) into single-fp16 padded tile images:
// img(L,nt,kt)[n*40+k] = (f16)W[kt*32+k][nt*128+n]; pad k=32..39 zeros.
// ---------------------------------------------------------------------------
__global__ void pack_w16(const float* __restrict__ w1,
                         const float* __restrict__ w2,
                         const float* __restrict__ w3,
                         _Float16* __restrict__ wp) {
    const int kt = blockIdx.x, nt = blockIdx.y, L = blockIdx.z;
    const float* W = (L == 0) ? w1 : ((L == 1) ? w2 : w3);
    __shared__ float tl[128 * 33];   // [n][k] transposed, padded
    const int tid = threadIdx.x;
    const int k  = tid >> 3;          // 0..31
    const int nc = (tid & 7) * 16;    // 0..112
    const float* src = W + (size_t)(kt * 32 + k) * HID + nt * 128 + nc;
    #pragma unroll
    for (int j = 0; j < 16; ++j) tl[(nc + j) * 33 + k] = src[j];
    __syncthreads();
    const size_t base = (size_t)(L * 1024 + nt * 64 + kt) * BIMG;
    for (int e = tid; e < BIMG; e += 256) {
        int n = e / 40, kk = e - n * 40;
        wp[base + e] = (kk < 32) ? (_Float16)tl[n * 33 + kk] : (_Float16)0.f;
    }
}

// ---------------------------------------------------------------------------
// MFMA GEMM v13 core (fp16), r8-proven: 32x128 wave tiles (unique A slice per
// wave -> minimal L2 A-traffic), distance-1 PF, partial-drain gate vmcnt(4),
// XCD-chunked bijective swizzle, optional fused layer-4 epilogue. FROZEN
// (passed rounds 8-10 unchanged; GATE4's count assumption has held for this
// exact code shape).
// ---------------------------------------------------------------------------
__launch_bounds__(256, 3)
__global__ void gemm_hl(const _Float16* __restrict__ Ahg,
                        const _Float16* __restrict__ Alg,
                        const _Float16* __restrict__ wp,
                        const float* __restrict__ bias,
                        _Float16* __restrict__ Chg,
                        _Float16* __restrict__ Clg,
                        int layer, int write_lo,
                        float* __restrict__ Amg4,
                        const float* __restrict__ w4g, int row0) {
    __shared__ _Float16 Bs[4][BIMG];   // 4 x 10240 B = 40 KB

    const int tid  = threadIdx.x;
    const int lane = tid & 63;
    const int wave = tid >> 6;
    const int quad = lane >> 4;
    const int lidx = lane & 15;

    const int nwg = (int)(gridDim.x * gridDim.y);
    const int L   = (int)(blockIdx.y * gridDim.x + blockIdx.x);
    const int F   = (L & 7) * (nwg >> 3) + (L >> 3);
    const int nt  = F & 15;
    const int mt  = F >> 4;

    const int mbase = wave * 32;        // each wave: 32 rows x 128 cols

    const char* gW = (const char*)(wp + (size_t)(layer * 1024 + nt * 64) * BIMG);

    const size_t abase = ((size_t)(mt * 64) << 12) + (size_t)(mbase >> 4) * 512 + (size_t)lane * 8;
    const _Float16* aH = Ahg + abase;
    const _Float16* aL = Alg + abase;

    f32x4 acc[2][8];
    #pragma unroll
    for (int i = 0; i < 2; ++i)
        #pragma unroll
        for (int j = 0; j < 8; ++j) acc[i][j] = (f32x4)0.f;

#define PF_B(KT, BUF) do {                                                            \
    const char* nW_ = gW + (size_t)(KT) * (BIMG * 2);                                 \
    char* dW_ = (char*)&Bs[BUF][0];                                                   \
    for (int t = wave; t < 10; t += 4) {                                              \
        __builtin_amdgcn_global_load_lds(                                             \
            (const __attribute__((address_space(1))) unsigned int*)(nW_ + t * 1024 + lane * 16), \
            (__attribute__((address_space(3))) unsigned int*)(dW_ + t * 1024), 16, 0, 0); \
    }                                                                                 \
} while (0)

#define LD_A(KT, H, Lo) do {                                                          \
    const size_t ak_ = (size_t)(KT) << 12;                                            \
    _Pragma("unroll")                                                                 \
    for (int mm = 0; mm < 2; ++mm) {                                                  \
        H[mm]  = *(const f16x8*)(aH + ak_ + mm * 512);                                \
        Lo[mm] = *(const f16x8*)(aL + ak_ + mm * 512);                                \
    }                                                                                 \
} while (0)

#define LD_B(BUF, BF) do {                                                            \
    _Pragma("unroll")                                                                 \
    for (int nn = 0; nn < 8; ++nn) {                                                  \
        int r_ = nn * 16 + lidx;                                                      \
        BF[nn] = *(const f16x8*)(&Bs[BUF][r_ * 40 + quad * 8]);                       \
    }                                                                                 \
} while (0)

#define MFMA32(AH, AL, BF) do {                                                       \
    _Pragma("unroll")                                                                 \
    for (int mm = 0; mm < 2; ++mm)                                                    \
        _Pragma("unroll")                                                             \
        for (int nn = 0; nn < 8; ++nn) {                                              \
            acc[mm][nn] = __builtin_amdgcn_mfma_f32_16x16x32_f16(AH[mm], BF[nn], acc[mm][nn], 0, 0, 0); \
            acc[mm][nn] = __builtin_amdgcn_mfma_f32_16x16x32_f16(AL[mm], BF[nn], acc[mm][nn], 0, 0, 0); \
        }                                                                             \
} while (0)

#define GATE4() do {                                                                  \
    asm volatile("s_waitcnt vmcnt(4)" ::: "memory");                                  \
    __builtin_amdgcn_sched_barrier(0);                                                \
    __builtin_amdgcn_s_barrier();                                                     \
    __builtin_amdgcn_sched_barrier(0);                                                \
} while (0)

#define SUPER(S, P, DO_PF, DO_A2) do {                                                \
    f16x8 bfr0_[8];                                                                   \
    LD_B(2 * (P), bfr0_);                                                             \
    if (DO_PF) { PF_B(2 * (S) + 2, 2 * ((P) ^ 1)); PF_B(2 * (S) + 3, 2 * ((P) ^ 1) + 1); } \
    LD_A(2 * (S) + 1, nah, nal);                                                      \
    MFMA32(cah, cal, bfr0_);                                                          \
    f16x8 bfr1_[8];                                                                   \
    LD_B(2 * (P) + 1, bfr1_);                                                         \
    if (DO_A2) LD_A(2 * (S) + 2, cah, cal);                                           \
    MFMA32(nah, nal, bfr1_);                                                          \
    GATE4();                                                                          \
} while (0)

    f16x8 cah[2], cal[2], nah[2], nal[2];

    PF_B(0, 0);
    PF_B(1, 1);
    LD_A(0, cah, cal);
    __syncthreads();

    for (int ss = 0; ss < 15; ++ss) {
        SUPER(2 * ss,     0, 1, 1);
        SUPER(2 * ss + 1, 1, 1, 1);
    }
    SUPER(30, 0, 1, 1);
    SUPER(31, 1, 0, 0);

#undef SUPER
#undef GATE4
#undef MFMA32
#undef LD_B
#undef LD_A
#undef PF_B

    if (Amg4) {
        // fused layer 4: h3 = relu(acc + b3); partial = h3 . w4 per row;
        // 16-lane reduce; one atomicAdd per row. relu(x+b4) applied in mg_all.
        float w4v[8], bv[8];
        #pragma unroll
        for (int nn = 0; nn < 8; ++nn) {
            const int col = nt * 128 + nn * 16 + lidx;
            w4v[nn] = w4g[col];
            bv[nn]  = bias[col];
        }
        #pragma unroll
        for (int mm = 0; mm < 2; ++mm) {
            #pragma unroll
            for (int r = 0; r < 4; ++r) {
                float p = 0.f;
                #pragma unroll
                for (int nn = 0; nn < 8; ++nn) {
                    float v = acc[mm][nn][r] + bv[nn];
                    v = v > 0.f ? v : 0.f;
                    p += v * w4v[nn];
                }
                #pragma unroll
                for (int off = 1; off <= 8; off <<= 1)
                    p += __shfl_xor(p, off, 16);
                if (lidx == 0) {
                    const int grow = row0 + mt * 128 + mbase + mm * 16 + quad * 4 + r;
                    if (grow < MPTS) atomicAdd(Amg4 + grow, p);
                }
            }
        }
        return;
    }

    // epilogue: C/D layout col=lane&15, row=quad*4+reg; write P-layout pair
    #pragma unroll
    for (int nn = 0; nn < 8; ++nn) {
        const int col = nt * 128 + nn * 16 + lidx;           // k of next layer
        const float bv = bias[col];
        const int kt2 = col >> 5, quad2 = (col >> 3) & 3, j2 = col & 7;
        const size_t cb = ((size_t)(mt * 64 + kt2) << 12) + quad2 * 128 + j2;
        #pragma unroll
        for (int mm = 0; mm < 2; ++mm) {
            const int rowg = (mbase >> 4) + mm;             // rowgrp
            #pragma unroll
            for (int r = 0; r < 4; ++r) {
                const int lidx2 = quad * 4 + r;             // row & 15
                float v = acc[mm][nn][r] + bv;
                v = v > 0.f ? v : 0.f;
                _Float16 hs = (_Float16)v;
                const size_t idx = cb + rowg * 512 + lidx2 * 8;
                Chg[idx] = hs;
                if (write_lo) Clg[idx] = (_Float16)(v - (float)hs);
            }
        }
    }
}

// ---------------------------------------------------------------------------
// MFMA GEMM v16 fused-L0 (r12): COMP pipelined one superstep ahead (the r11
// lever), but the gate is FULL-DRAIN vmcnt(0) -- correct by construction.
// r11's vmcnt(4) gate raced: its count assumed program-order vmem issue, and
// the compiler reordered the plain LDW global loads vs the global_load_lds
// prefetches, leaving PFs in flight across the barrier (intermittent stale-B
// reads -> replay divergence). vmcnt(0) makes no ordering assumption; r7
// measured partial-vs-full drain as neutral, so the cost is ~nil.
// Invariant: enter superstep s with A(2s) fragments BUILT (cah/cal) and
// w0/b0(2s+1) in wA*. COMP for A(2s+2) runs pre-gate (overlaps drain);
// cluster 1 fires immediately post-barrier. Arithmetic identical to layer0p.
// ---------------------------------------------------------------------------
__launch_bounds__(256, 3)
__global__ void gemm_f0(const float* __restrict__ xs,
                        const float* __restrict__ w0f,
                        const float* __restrict__ b0f,
                        const _Float16* __restrict__ wp,
                        const float* __restrict__ bias,
                        _Float16* __restrict__ Chg,
                        _Float16* __restrict__ Clg, int row0) {
    __shared__ _Float16 Bs[4][BIMG];   // 4 x 10240 B = 40 KB

    const int tid  = threadIdx.x;
    const int lane = tid & 63;
    const int wave = tid >> 6;
    const int quad = lane >> 4;
    const int lidx = lane & 15;

    const int nwg = (int)(gridDim.x * gridDim.y);
    const int L   = (int)(blockIdx.y * gridDim.x + blockIdx.x);
    const int F   = (L & 7) * (nwg >> 3) + (L >> 3);
    const int nt  = F & 15;
    const int mt  = F >> 4;

    const int mbase = wave * 32;

    const char* gW = (const char*)(wp + (size_t)(nt * 64) * BIMG);  // layer 0

    // per-lane row scalars (rows: mbase + mm*16 + lidx)
    const int g0 = row0 + mt * 128 + mbase + lidx;
    const float x0 = (g0 < MPTS) ? xs[g0] : 0.f;
    const float x1 = (g0 + 16 < MPTS) ? xs[g0 + 16] : 0.f;

    f32x4 acc[2][8];
    #pragma unroll
    for (int i = 0; i < 2; ++i)
        #pragma unroll
        for (int j = 0; j < 8; ++j) acc[i][j] = (f32x4)0.f;

#define PF0(KT, BUF) do {                                                             \
    const char* nW_ = gW + (size_t)(KT) * (BIMG * 2);                                 \
    char* dW_ = (char*)&Bs[BUF][0];                                                   \
    for (int t = wave; t < 10; t += 4) {                                              \
        __builtin_amdgcn_global_load_lds(                                             \
            (const __attribute__((address_space(1))) unsigned int*)(nW_ + t * 1024 + lane * 16), \
            (__attribute__((address_space(3))) unsigned int*)(dW_ + t * 1024), 16, 0, 0); \
    }                                                                                 \
} while (0)

#define LDW0(KT, WA, WB, BA, BB) do {                                                 \
    const int k0_ = (KT) * 32 + quad * 8;                                             \
    WA = *(const f32x4*)(w0f + k0_);                                                  \
    WB = *(const f32x4*)(w0f + k0_ + 4);                                              \
    BA = *(const f32x4*)(b0f + k0_);                                                  \
    BB = *(const f32x4*)(b0f + k0_ + 4);                                              \
} while (0)

// build hi/lo A fragments into H/L: identical arithmetic to old layer0p
#define COMP0_TO(H, L_, WA, WB, BA, BB) do {                                          \
    _Pragma("unroll")                                                                 \
    for (int mm = 0; mm < 2; ++mm) {                                                  \
        const float xm_ = mm ? x1 : x0;                                               \
        f16x8 h_, l_;                                                                 \
        _Pragma("unroll")                                                             \
        for (int j = 0; j < 4; ++j) {                                                 \
            float v_ = xm_ * WA[j] + BA[j];                                           \
            v_ = v_ > 0.f ? v_ : 0.f;                                                 \
            _Float16 hs_ = (_Float16)v_;                                              \
            h_[j] = hs_; l_[j] = (_Float16)(v_ - (float)hs_);                         \
        }                                                                             \
        _Pragma("unroll")                                                             \
        for (int j = 0; j < 4; ++j) {                                                 \
            float v_ = xm_ * WB[j] + BB[j];                                           \
            v_ = v_ > 0.f ? v_ : 0.f;                                                 \
            _Float16 hs_ = (_Float16)v_;                                              \
            h_[4 + j] = hs_; l_[4 + j] = (_Float16)(v_ - (float)hs_);                 \
        }                                                                             \
        H[mm] = h_; L_[mm] = l_;                                                      \
    }                                                                                 \
} while (0)

#define LDB0(BUF, BF) do {                                                            \
    _Pragma("unroll")                                                                 \
    for (int nn = 0; nn < 8; ++nn) {                                                  \
        int r_ = nn * 16 + lidx;                                                      \
        BF[nn] = *(const f16x8*)(&Bs[BUF][r_ * 40 + quad * 8]);                       \
    }                                                                                 \
} while (0)

#define MFMA0(AH, AL, BF) do {                                                        \
    _Pragma("unroll")                                                                 \
    for (int mm = 0; mm < 2; ++mm)                                                    \
        _Pragma("unroll")                                                             \
        for (int nn = 0; nn < 8; ++nn) {                                              \
            acc[mm][nn] = __builtin_amdgcn_mfma_f32_16x16x32_f16(AH[mm], BF[nn], acc[mm][nn], 0, 0, 0); \
            acc[mm][nn] = __builtin_amdgcn_mfma_f32_16x16x32_f16(AL[mm], BF[nn], acc[mm][nn], 0, 0, 0); \
        }                                                                             \
} while (0)

// Full drain: no vmem-issue-order assumption -> race-free by construction.
#define GATE0() do {                                                                  \
    asm volatile("s_waitcnt vmcnt(0)" ::: "memory");                                  \
    __builtin_amdgcn_sched_barrier(0);                                                \
    __builtin_amdgcn_s_barrier();                                                     \
    __builtin_amdgcn_sched_barrier(0);                                                \
} while (0)

// SUPERF(s): enter with A(2s) in cah/cal, w(2s+1) in wA*.
//   ds_read B[2s] | PF 2s+2,2s+3 | issue LDW(2s+2)->wB* | COMP A(2s+1)->nah |
//   MFMA c1(A(2s)) | ds_read B[2s+1] | issue LDW(2s+3)->wA* | MFMA c2(A(2s+1)) |
//   COMP A(2s+2)->cah (pre-gate, overlaps drain) | GATE vmcnt(0)
#define SUPERF(S, P, DO_PF, DO_W2, DO_W3, DO_NEXT) do {                               \
    f16x8 bfr0_[8];                                                                   \
    LDB0(2 * (P), bfr0_);                                                             \
    if (DO_PF) { PF0(2 * (S) + 2, 2 * ((P) ^ 1)); PF0(2 * (S) + 3, 2 * ((P) ^ 1) + 1); } \
    if (DO_W2) LDW0(2 * (S) + 2, wBa, wBb, bBa, bBb);                                 \
    COMP0_TO(nah, nal, wAa, wAb, bAa, bAb);     /* A(2s+1) */                         \
    MFMA0(cah, cal, bfr0_);                                                           \
    f16x8 bfr1_[8];                                                                   \
    LDB0(2 * (P) + 1, bfr1_);                                                         \
    if (DO_W3) LDW0(2 * (S) + 3, wAa, wAb, bAa, bAb);                                 \
    MFMA0(nah, nal, bfr1_);                                                           \
    if (DO_NEXT) COMP0_TO(cah, cal, wBa, wBb, bBa, bBb);   /* A(2s+2) */              \
    GATE0();                                                                          \
} while (0)

    f16x8 cah[2], cal[2], nah[2], nal[2];
    f32x4 wAa, wAb, bAa, bAb, wBa, wBb, bBa, bBb;

    // prologue: PF images 0,1; load w(0)->wB*, w(1)->wA*; build A(0).
    PF0(0, 0);
    PF0(1, 1);
    LDW0(0, wBa, wBb, bBa, bBb);
    LDW0(1, wAa, wAb, bAa, bAb);
    COMP0_TO(cah, cal, wBa, wBb, bBa, bBb);     // A(0)
    __syncthreads();

    for (int ss = 0; ss < 15; ++ss) {
        SUPERF(2 * ss,     0, 1, 1, 1, 1);
        SUPERF(2 * ss + 1, 1, 1, 1, 1, 1);
    }
    SUPERF(30, 0, 1, 1, 1, 1);
    SUPERF(31, 1, 0, 0, 0, 0);

#undef SUPERF
#undef GATE0
#undef MFMA0
#undef LDB0
#undef COMP0_TO
#undef LDW0
#undef PF0

    // epilogue: write h1 hi/lo pair in P-layout
    #pragma unroll
    for (int nn = 0; nn < 8; ++nn) {
        const int col = nt * 128 + nn * 16 + lidx;
        const float bv = bias[col];
        const int kt2 = col >> 5, quad2 = (col >> 3) & 3, j2 = col & 7;
        const size_t cb = ((size_t)(mt * 64 + kt2) << 12) + quad2 * 128 + j2;
        #pragma unroll
        for (int mm = 0; mm < 2; ++mm) {
            const int rowg = (mbase >> 4) + mm;
            #pragma unroll
            for (int r = 0; r < 4; ++r) {
                const int lidx2 = quad * 4 + r;
                float v = acc[mm][nn][r] + bv;
                v = v > 0.f ? v : 0.f;
                _Float16 hs = (_Float16)v;
                const size_t idx = cb + rowg * 512 + lidx2 * 8;
                Chg[idx] = hs;
                Clg[idx] = (_Float16)(v - (float)hs);
            }
        }
    }
}

// ---------------------------------------------------------------------------
// Fallback fp32 path (ws too small for packed images)
// ---------------------------------------------------------------------------
__global__ void layer0f(const float* __restrict__ xs, const float* __restrict__ w0,
                        const float* __restrict__ b0, float* __restrict__ A, int row0) {
    const int r = blockIdx.x;
    const int j = threadIdx.x * 8;
    const float x = (row0 + r < MPTS) ? xs[row0 + r] : 0.f;
    float* out = A + (size_t)r * HID + j;
    #pragma unroll
    for (int q = 0; q < 8; ++q) {
        float v = x * w0[j + q] + b0[j + q];
        out[q] = v > 0.f ? v : 0.f;
    }
}

__launch_bounds__(256)
__global__ void gemm_valu(const float* __restrict__ A, const float* __restrict__ W,
                          const float* __restrict__ bias, float* __restrict__ C) {
    __shared__ float As[16][132];
    __shared__ float Ws[16][132];
    const int tid = threadIdx.x;
    const int tx = tid & 15, ty = tid >> 4;
    const int n0 = blockIdx.x * 128;
    const int m0 = blockIdx.y * 128;
    const int am = tid & 127, ak = (tid >> 7) * 8;
    const int wn = (tid & 15) * 8, wk = tid >> 4;
    const float* aptr = A + (size_t)(m0 + am) * HID + ak;
    const float* wptr = W + (size_t)wk * HID + n0 + wn;
    float acc[8][8];
    #pragma unroll
    for (int i = 0; i < 8; ++i)
        #pragma unroll
        for (int j = 0; j < 8; ++j) acc[i][j] = 0.f;
    for (int k0 = 0; k0 < HID; k0 += 16) {
        f32x4 a0 = *(const f32x4*)(aptr + k0);
        f32x4 a1 = *(const f32x4*)(aptr + k0 + 4);
        f32x4 w0v = *(const f32x4*)(wptr + (size_t)k0 * HID);
        f32x4 w1v = *(const f32x4*)(wptr + (size_t)k0 * HID + 4);
        __syncthreads();
        As[ak + 0][am] = a0[0]; As[ak + 1][am] = a0[1];
        As[ak + 2][am] = a0[2]; As[ak + 3][am] = a0[3];
        As[ak + 4][am] = a1[0]; As[ak + 5][am] = a1[1];
        As[ak + 6][am] = a1[2]; As[ak + 7][am] = a1[3];
        *(f32x4*)&Ws[wk][wn]     = w0v;
        *(f32x4*)&Ws[wk][wn + 4] = w1v;
        __syncthreads();
        #pragma unroll
        for (int kk = 0; kk < 16; ++kk) {
            f32x4 av0 = *(const f32x4*)&As[kk][ty * 8];
            f32x4 av1 = *(const f32x4*)&As[kk][ty * 8 + 4];
            f32x4 bv0 = *(const f32x4*)&Ws[kk][tx * 8];
            f32x4 bv1 = *(const f32x4*)&Ws[kk][tx * 8 + 4];
            float a[8] = {av0[0], av0[1], av0[2], av0[3], av1[0], av1[1], av1[2], av1[3]};
            float b[8] = {bv0[0], bv0[1], bv0[2], bv0[3], bv1[0], bv1[1], bv1[2], bv1[3]};
            #pragma unroll
            for (int i = 0; i < 8; ++i)
                #pragma unroll
                for (int j = 0; j < 8; ++j) acc[i][j] += a[i] * b[j];
        }
    }
    #pragma unroll
    for (int i = 0; i < 8; ++i) {
        const int m = m0 + ty * 8 + i;
        #pragma unroll
        for (int jc = 0; jc < 2; ++jc) {
            const int n = n0 + tx * 8 + jc * 4;
            f32x4 v4;
            #pragma unroll
            for (int q = 0; q < 4; ++q) {
                float v = acc[i][jc * 4 + q] + bias[n + q];
                v4[q] = v > 0.f ? v : 0.f;
            }
            *(f32x4*)(C + (size_t)m * HID + n) = v4;
        }
    }
}

__global__ void layer4f(const float* __restrict__ A, const float* __restrict__ w4,
                        const float* __restrict__ b4, float* __restrict__ Amg, int row0) {
    const int lane = threadIdx.x & 63;
    const int wave = threadIdx.x >> 6;
    const int r    = blockIdx.x * 4 + wave;
    if (row0 + r >= MPTS) return;
    const float* ap = A + (size_t)r * HID;
    float s = 0.f;
    #pragma unroll
    for (int c = 0; c < 8; ++c) {
        const int col = c * 256 + lane * 4;
        f32x4 av = *(const f32x4*)(ap + col);
        f32x4 wv = *(const f32x4*)(w4 + col);
        s += av[0] * wv[0] + av[1] * wv[1] + av[2] * wv[2] + av[3] * wv[3];
    }
    #pragma unroll
    for (int off = 32; off; off >>= 1) s += __shfl_down(s, off);
    if (lane == 0) {
        float v = s + b4[0];
        Amg[row0 + r] = v > 0.f ? v : 0.f;
    }
}

// ---------------------------------------------------------------------------
// Fused multigrid cascade: all 5 levels in ONE kernel (r10-proven). Each
// block back-traces its 256-output dependency cone through LDS. Bitwise
// identical to the old 5x mg_level chain. b4p null => f = identity.
// ---------------------------------------------------------------------------
__global__ void mg_all(const float* __restrict__ Amg, float* __restrict__ outf,
                       const int* __restrict__ nbrs, const float* __restrict__ b4p) {
    __shared__ float Lb[16], L0[24], L1[40], L2[72], L3[136];
    const int t = threadIdx.x;
    const int NFIN = 524289;
    const int o0 = (int)blockIdx.x * 256;
    const float b4v = b4p ? b4p[0] : 0.f;
    const int stride = (nbrs[1] == 0 && nbrs[3] == 0 && nbrs[5] == 0) ? 2 : 1;

#define MGF(x) (b4p ? fmaxf((x) + b4v, 0.f) : (x))

    const int nin[5] = {16385, 32769, 65537, 131073, 262145};
    int OS4 = o0;
    int OC4 = (NFIN - o0 < 256) ? (NFIN - o0) : 256;
    int IS4 = (OS4 > 0) ? ((OS4 - 1) >> 1) : 0;
    int IE4 = ((OS4 + OC4) >> 1) + 1; if (IE4 > nin[4]) IE4 = nin[4];
    int OS3 = IS4, OC3 = IE4 - IS4;
    int IS3 = (OS3 > 0) ? ((OS3 - 1) >> 1) : 0;
    int IE3 = ((OS3 + OC3) >> 1) + 1; if (IE3 > nin[3]) IE3 = nin[3];
    int OS2 = IS3, OC2 = IE3 - IS3;
    int IS2 = (OS2 > 0) ? ((OS2 - 1) >> 1) : 0;
    int IE2 = ((OS2 + OC2) >> 1) + 1; if (IE2 > nin[2]) IE2 = nin[2];
    int OS1 = IS2, OC1 = IE2 - IS2;
    int IS1 = (OS1 > 0) ? ((OS1 - 1) >> 1) : 0;
    int IE1 = ((OS1 + OC1) >> 1) + 1; if (IE1 > nin[1]) IE1 = nin[1];
    int OS0 = IS1, OC0 = IE1 - IS1;
    int IS0 = (OS0 > 0) ? ((OS0 - 1) >> 1) : 0;
    int IE0 = ((OS0 + OC0) >> 1) + 1; if (IE0 > nin[0]) IE0 = nin[0];
    int BS = IS0, BC = IE0 - IS0;

    if (t < BC) Lb[t] = MGF(Amg[40 + BS + t]);
    __syncthreads();

#define MG_STAGE(LVL, INARR, INS, OUTARR, OS_, OC_) do {                              \
    if (t < (OC_)) {                                                                  \
        const int gj = (OS_) + t;                                                     \
        const int h = gj >> 1;                                                        \
        float v;                                                                      \
        if (gj & 1) v = 0.5f * (INARR[h - (INS)] + INARR[h + 1 - (INS)]);             \
        else        v = INARR[h - (INS)];                                             \
        _Pragma("unroll")                                                             \
        for (int t8 = 0; t8 < 8; ++t8) {                                              \
            const int idx = nbrs[((LVL) * 8 + t8) * stride];                          \
            if (idx == gj) v = MGF(Amg[8 * (4 - (LVL)) + t8]);                        \
        }                                                                             \
        OUTARR[t] = v;                                                                \
    }                                                                                 \
    __syncthreads();                                                                  \
} while (0)

    MG_STAGE(0, Lb, BS,  L0, OS0, OC0);
    MG_STAGE(1, L0, OS0, L1, OS1, OC1);
    MG_STAGE(2, L1, OS1, L2, OS2, OC2);
    MG_STAGE(3, L2, OS2, L3, OS3, OC3);

    if (t < OC4) {
        const int gj = OS4 + t;
        const int h = gj >> 1;
        float v;
        if (gj & 1) v = 0.5f * (L3[h - OS3] + L3[h + 1 - OS3]);
        else        v = L3[h - OS3];
        #pragma unroll
        for (int t8 = 0; t8 < 8; ++t8) {
            const int idx = nbrs[(4 * 8 + t8) * stride];
            if (idx == gj) v = MGF(Amg[t8]);
        }
        outf[gj] = v;
    }

#undef MG_STAGE
#undef MGF
}

// ---------------------------------------------------------------------------
extern "C" void kernel_launch(void* const* d_in, const int* in_sizes, int n_in,
                              void* d_out, int out_size, void* d_ws, size_t ws_size,
                              hipStream_t stream) {
    // ---- input order detection: dict (documented) / signature / alphabetical
    int iXS=0, iNB=1, iW0=4, iB0=5, iW1=6, iB1=7, iW2=8, iB2=9,
        iW3=10, iB3=11, iW4=12, iB4=13;                       // dict default
    if (n_in >= 14) {
        if (in_sizes[0] == HID) {
            iB0=0; iB1=1; iB2=2; iB3=3; iB4=4; iNB=7;
            iW0=8; iW1=9; iW2=10; iW3=11; iW4=12; iXS=13;
        } else if (!(in_sizes[1] == 40 || in_sizes[1] == 80)) {
            iXS=0; iW0=1; iB0=2; iW1=3; iB1=4; iW2=5; iB2=6;
            iW3=7; iB3=8; iW4=9; iB4=10; iNB=11;
        }
    }
    const float* xs = (const float*)d_in[iXS];
    const int* nbrs = (const int*)d_in[iNB];
    const float* w0 = (const float*)d_in[iW0];
    const float* b0 = (const float*)d_in[iB0];
    const float* w1 = (const float*)d_in[iW1];
    const float* b1 = (const float*)d_in[iB1];
    const float* w2 = (const float*)d_in[iW2];
    const float* b2 = (const float*)d_in[iB2];
    const float* w3 = (const float*)d_in[iW3];
    const float* b3 = (const float*)d_in[iB3];
    const float* w4 = (const float*)d_in[iW4];
    const float* b4 = (const float*)d_in[iB4];

    // ---- workspace layout ----
    char* ws = (char*)d_ws;
    const size_t szAmg = 66048;
    const size_t szAh1 = 524544;
    const size_t szAh2 = 1048832;
    float* Amg = (float*)(ws);
    float* ahA = (float*)(ws + szAmg);
    float* ahB = (float*)(ws + szAmg + szAh1);
    const size_t casc_end = szAmg + szAh1 + szAh2;       // 1,639,424
    const size_t szW    = (size_t)3 * 1024 * BIMG * 2;   // 31,457,280 (fp16)
    const size_t per_tile = 2ull * 128 * HID * 4;        // 2 MB (4 fp16 act bufs)

    const int use_mfma = (ws_size >= casc_end + szW + per_tile) ? 1 : 0;

    _Float16* wp = (_Float16*)(ws + casc_end);
    const size_t buf_start = use_mfma ? (casc_end + szW) : casc_end;

    size_t avail = ws_size - buf_start;
    int CT = (int)(avail / per_tile);
    if (CT < 1) CT = 1;
    if (CT > MTILES) CT = MTILES;   // single chunk when workspace allows

    if (use_mfma) {
        const size_t half = (size_t)CT * 128 * HID;       // f16 elems per buffer
        _Float16* bAh = (_Float16*)(ws + buf_start);
        _Float16* bAl = bAh + half;
        _Float16* bBh = bAh + 2 * half;
        _Float16* bBl = bAh + 3 * half;

        // fused layer-4 accumulates into Amg -> zero it (stream-ordered).
        hipMemsetAsync(Amg, 0, (size_t)MPTS * sizeof(float), stream);

        pack_w16<<<dim3(KTIL, NTIL, 3), 256, 0, stream>>>(w1, w2, w3, wp);

        for (int t0 = 0; t0 < MTILES; t0 += CT) {
            int tiles = (MTILES - t0 < CT) ? (MTILES - t0) : CT;
            int row0 = t0 * 128;
            dim3 ggrid(NTIL, tiles);
            // layer 0 fused with the xs->A0 rank-1 expansion (no layer0p)
            gemm_f0<<<ggrid, 256, 0, stream>>>(xs, w0, b0, wp, b1, bBh, bBl, row0);
            gemm_hl<<<ggrid, 256, 0, stream>>>(bBh, bBl, wp, b2, bAh, bAl, 1, 1,
                                               nullptr, nullptr, 0);
            // layer 2->3 gemm with fused layer-4 dot (no C write, no layer4p)
            gemm_hl<<<ggrid, 256, 0, stream>>>(bAh, bAl, wp, b3, bBh, bBl, 2, 0,
                                               Amg, w4, row0);
        }
    } else {
        float* bufA = (float*)(ws + buf_start);
        float* bufB = (float*)(ws + buf_start + (size_t)CT * 128 * HID * 4);
        for (int t0 = 0; t0 < MTILES; t0 += CT) {
            int tiles = (MTILES - t0 < CT) ? (MTILES - t0) : CT;
            int row0 = t0 * 128;
            layer0f<<<dim3(tiles * 128), 256, 0, stream>>>(xs, w0, b0, bufA, row0);
            dim3 ggrid(NTIL, tiles);
            gemm_valu<<<ggrid, 256, 0, stream>>>(bufA, w1, b1, bufB);
            gemm_valu<<<ggrid, 256, 0, stream>>>(bufB, w2, b2, bufA);
            gemm_valu<<<ggrid, 256, 0, stream>>>(bufA, w3, b3, bufB);
            layer4f<<<dim3(tiles * 32), 256, 0, stream>>>(bufB, w4, b4, Amg, row0);
        }
    }

    // fused multigrid cascade: one kernel for all 5 levels (final = 524289).
    const float* b4p = use_mfma ? b4 : nullptr;
    mg_all<<<dim3((524289 + 255) / 256), 256, 0, stream>>>(
        Amg, (float*)d_out, nbrs, b4p);
    (void)ahA; (void)ahB;
    (void)out_size;
}

// Round 13
// 877.729 us; speedup vs baseline: 1.0235x; 1.0235x over previous
//
#include <hip/hip_runtime.h>
#include <stdint.h>

#define HID    2048
#define MPTS   16425
#define MTILES 129    // ceil(16425/128)
#define NTIL   16     // 2048/128
#define KTIL   64     // 2048/32
#define BIMG   5120   // f16 elems per packed padded B tile image (128 rows * 40)

typedef float    f32x4 __attribute__((ext_vector_type(4)));
typedef _Float16 f16x8 __attribute__((ext_vector_type(8)));

// P-layout (A-operand fragment order) for activations:
// elem(row, k) -> linear ((tile*64+kt)<<12) + rowgrp*512 + quad*128 + lidx*8 + j
//   tile=row>>7, rowgrp=(row>>4)&7, lidx=row&15, kt=k>>5, quad=(k>>3)&3, j=k&7
// Consumer wave A-frag load = base + lane*8 halves (1KB fully coalesced).

// ---------------------------------------------------------------------------
// Pack fp32 W (K x N row-major) into single-fp16 padded tile images:
// img(L,nt,kt)[n*40+k] = (f16)W[kt*32+k][nt*128+n]; pad k=32..39 zeros.
// ---------------------------------------------------------------------------
__global__ void pack_w16(const float* __restrict__ w1,
                         const float* __restrict__ w2,
                         const float* __restrict__ w3,
                         _Float16* __restrict__ wp) {
    const int kt = blockIdx.x, nt = blockIdx.y, L = blockIdx.z;
    const float* W = (L == 0) ? w1 : ((L == 1) ? w2 : w3);
    __shared__ float tl[128 * 33];   // [n][k] transposed, padded
    const int tid = threadIdx.x;
    const int k  = tid >> 3;          // 0..31
    const int nc = (tid & 7) * 16;    // 0..112
    const float* src = W + (size_t)(kt * 32 + k) * HID + nt * 128 + nc;
    #pragma unroll
    for (int j = 0; j < 16; ++j) tl[(nc + j) * 33 + k] = src[j];
    __syncthreads();
    const size_t base = (size_t)(L * 1024 + nt * 64 + kt) * BIMG;
    for (int e = tid; e < BIMG; e += 256) {
        int n = e / 40, kk = e - n * 40;
        wp[base + e] = (kk < 32) ? (_Float16)tl[n * 33 + kk] : (_Float16)0.f;
    }
}

// ---------------------------------------------------------------------------
// MFMA GEMM v13 core (fp16), r8-proven: 32x128 wave tiles (unique A slice per
// wave -> minimal L2 A-traffic), distance-1 PF, partial-drain gate vmcnt(4),
// XCD-chunked bijective swizzle, optional fused layer-4 epilogue. FROZEN.
// ---------------------------------------------------------------------------
__launch_bounds__(256, 3)
__global__ void gemm_hl(const _Float16* __restrict__ Ahg,
                        const _Float16* __restrict__ Alg,
                        const _Float16* __restrict__ wp,
                        const float* __restrict__ bias,
                        _Float16* __restrict__ Chg,
                        _Float16* __restrict__ Clg,
                        int layer, int write_lo,
                        float* __restrict__ Amg4,
                        const float* __restrict__ w4g, int row0) {
    __shared__ _Float16 Bs[4][BIMG];   // 4 x 10240 B = 40 KB

    const int tid  = threadIdx.x;
    const int lane = tid & 63;
    const int wave = tid >> 6;
    const int quad = lane >> 4;
    const int lidx = lane & 15;

    const int nwg = (int)(gridDim.x * gridDim.y);
    const int L   = (int)(blockIdx.y * gridDim.x + blockIdx.x);
    const int F   = (L & 7) * (nwg >> 3) + (L >> 3);
    const int nt  = F & 15;
    const int mt  = F >> 4;

    const int mbase = wave * 32;        // each wave: 32 rows x 128 cols

    const char* gW = (const char*)(wp + (size_t)(layer * 1024 + nt * 64) * BIMG);

    const size_t abase = ((size_t)(mt * 64) << 12) + (size_t)(mbase >> 4) * 512 + (size_t)lane * 8;
    const _Float16* aH = Ahg + abase;
    const _Float16* aL = Alg + abase;

    f32x4 acc[2][8];
    #pragma unroll
    for (int i = 0; i < 2; ++i)
        #pragma unroll
        for (int j = 0; j < 8; ++j) acc[i][j] = (f32x4)0.f;

#define PF_B(KT, BUF) do {                                                            \
    const char* nW_ = gW + (size_t)(KT) * (BIMG * 2);                                 \
    char* dW_ = (char*)&Bs[BUF][0];                                                   \
    for (int t = wave; t < 10; t += 4) {                                              \
        __builtin_amdgcn_global_load_lds(                                             \
            (const __attribute__((address_space(1))) unsigned int*)(nW_ + t * 1024 + lane * 16), \
            (__attribute__((address_space(3))) unsigned int*)(dW_ + t * 1024), 16, 0, 0); \
    }                                                                                 \
} while (0)

#define LD_A(KT, H, Lo) do {                                                          \
    const size_t ak_ = (size_t)(KT) << 12;                                            \
    _Pragma("unroll")                                                                 \
    for (int mm = 0; mm < 2; ++mm) {                                                  \
        H[mm]  = *(const f16x8*)(aH + ak_ + mm * 512);                                \
        Lo[mm] = *(const f16x8*)(aL + ak_ + mm * 512);                                \
    }                                                                                 \
} while (0)

#define LD_B(BUF, BF) do {                                                            \
    _Pragma("unroll")                                                                 \
    for (int nn = 0; nn < 8; ++nn) {                                                  \
        int r_ = nn * 16 + lidx;                                                      \
        BF[nn] = *(const f16x8*)(&Bs[BUF][r_ * 40 + quad * 8]);                       \
    }                                                                                 \
} while (0)

#define MFMA32(AH, AL, BF) do {                                                       \
    _Pragma("unroll")                                                                 \
    for (int mm = 0; mm < 2; ++mm)                                                    \
        _Pragma("unroll")                                                             \
        for (int nn = 0; nn < 8; ++nn) {                                              \
            acc[mm][nn] = __builtin_amdgcn_mfma_f32_16x16x32_f16(AH[mm], BF[nn], acc[mm][nn], 0, 0, 0); \
            acc[mm][nn] = __builtin_amdgcn_mfma_f32_16x16x32_f16(AL[mm], BF[nn], acc[mm][nn], 0, 0, 0); \
        }                                                                             \
} while (0)

#define GATE4() do {                                                                  \
    asm volatile("s_waitcnt vmcnt(4)" ::: "memory");                                  \
    __builtin_amdgcn_sched_barrier(0);                                                \
    __builtin_amdgcn_s_barrier();                                                     \
    __builtin_amdgcn_sched_barrier(0);                                                \
} while (0)

#define SUPER(S, P, DO_PF, DO_A2) do {                                                \
    f16x8 bfr0_[8];                                                                   \
    LD_B(2 * (P), bfr0_);                                                             \
    if (DO_PF) { PF_B(2 * (S) + 2, 2 * ((P) ^ 1)); PF_B(2 * (S) + 3, 2 * ((P) ^ 1) + 1); } \
    LD_A(2 * (S) + 1, nah, nal);                                                      \
    MFMA32(cah, cal, bfr0_);                                                          \
    f16x8 bfr1_[8];                                                                   \
    LD_B(2 * (P) + 1, bfr1_);                                                         \
    if (DO_A2) LD_A(2 * (S) + 2, cah, cal);                                           \
    MFMA32(nah, nal, bfr1_);                                                          \
    GATE4();                                                                          \
} while (0)

    f16x8 cah[2], cal[2], nah[2], nal[2];

    PF_B(0, 0);
    PF_B(1, 1);
    LD_A(0, cah, cal);
    __syncthreads();

    for (int ss = 0; ss < 15; ++ss) {
        SUPER(2 * ss,     0, 1, 1);
        SUPER(2 * ss + 1, 1, 1, 1);
    }
    SUPER(30, 0, 1, 1);
    SUPER(31, 1, 0, 0);

#undef SUPER
#undef GATE4
#undef MFMA32
#undef LD_B
#undef LD_A
#undef PF_B

    if (Amg4) {
        // fused layer 4: h3 = relu(acc + b3); partial = h3 . w4 per row;
        // 16-lane reduce; one atomicAdd per row. relu(x+b4) applied in mg_all.
        float w4v[8], bv[8];
        #pragma unroll
        for (int nn = 0; nn < 8; ++nn) {
            const int col = nt * 128 + nn * 16 + lidx;
            w4v[nn] = w4g[col];
            bv[nn]  = bias[col];
        }
        #pragma unroll
        for (int mm = 0; mm < 2; ++mm) {
            #pragma unroll
            for (int r = 0; r < 4; ++r) {
                float p = 0.f;
                #pragma unroll
                for (int nn = 0; nn < 8; ++nn) {
                    float v = acc[mm][nn][r] + bv[nn];
                    v = v > 0.f ? v : 0.f;
                    p += v * w4v[nn];
                }
                #pragma unroll
                for (int off = 1; off <= 8; off <<= 1)
                    p += __shfl_xor(p, off, 16);
                if (lidx == 0) {
                    const int grow = row0 + mt * 128 + mbase + mm * 16 + quad * 4 + r;
                    if (grow < MPTS) atomicAdd(Amg4 + grow, p);
                }
            }
        }
        return;
    }

    // epilogue: C/D layout col=lane&15, row=quad*4+reg; write P-layout pair
    #pragma unroll
    for (int nn = 0; nn < 8; ++nn) {
        const int col = nt * 128 + nn * 16 + lidx;           // k of next layer
        const float bv = bias[col];
        const int kt2 = col >> 5, quad2 = (col >> 3) & 3, j2 = col & 7;
        const size_t cb = ((size_t)(mt * 64 + kt2) << 12) + quad2 * 128 + j2;
        #pragma unroll
        for (int mm = 0; mm < 2; ++mm) {
            const int rowg = (mbase >> 4) + mm;             // rowgrp
            #pragma unroll
            for (int r = 0; r < 4; ++r) {
                const int lidx2 = quad * 4 + r;             // row & 15
                float v = acc[mm][nn][r] + bv;
                v = v > 0.f ? v : 0.f;
                _Float16 hs = (_Float16)v;
                const size_t idx = cb + rowg * 512 + lidx2 * 8;
                Chg[idx] = hs;
                if (write_lo) Clg[idx] = (_Float16)(v - (float)hs);
            }
        }
    }
}

// ---------------------------------------------------------------------------
// MFMA GEMM v14 fused-L0 variant (r9/r10-proven): A0 = relu(xs*w0+b0) is
// RANK-1, computed in-register. Removes A0 HBM write/read + layer0p
// dispatches. FROZEN at the r10-measured-best shape (r11/r12 COMP-ahead
// variants regressed or raced -- reverted).
// ---------------------------------------------------------------------------
__launch_bounds__(256, 3)
__global__ void gemm_f0(const float* __restrict__ xs,
                        const float* __restrict__ w0f,
                        const float* __restrict__ b0f,
                        const _Float16* __restrict__ wp,
                        const float* __restrict__ bias,
                        _Float16* __restrict__ Chg,
                        _Float16* __restrict__ Clg, int row0) {
    __shared__ _Float16 Bs[4][BIMG];   // 4 x 10240 B = 40 KB

    const int tid  = threadIdx.x;
    const int lane = tid & 63;
    const int wave = tid >> 6;
    const int quad = lane >> 4;
    const int lidx = lane & 15;

    const int nwg = (int)(gridDim.x * gridDim.y);
    const int L   = (int)(blockIdx.y * gridDim.x + blockIdx.x);
    const int F   = (L & 7) * (nwg >> 3) + (L >> 3);
    const int nt  = F & 15;
    const int mt  = F >> 4;

    const int mbase = wave * 32;

    const char* gW = (const char*)(wp + (size_t)(nt * 64) * BIMG);  // layer 0

    // per-lane row scalars (rows: mbase + mm*16 + lidx)
    const int g0 = row0 + mt * 128 + mbase + lidx;
    const float x0 = (g0 < MPTS) ? xs[g0] : 0.f;
    const float x1 = (g0 + 16 < MPTS) ? xs[g0 + 16] : 0.f;

    f32x4 acc[2][8];
    #pragma unroll
    for (int i = 0; i < 2; ++i)
        #pragma unroll
        for (int j = 0; j < 8; ++j) acc[i][j] = (f32x4)0.f;

#define PF0(KT, BUF) do {                                                             \
    const char* nW_ = gW + (size_t)(KT) * (BIMG * 2);                                 \
    char* dW_ = (char*)&Bs[BUF][0];                                                   \
    for (int t = wave; t < 10; t += 4) {                                              \
        __builtin_amdgcn_global_load_lds(                                             \
            (const __attribute__((address_space(1))) unsigned int*)(nW_ + t * 1024 + lane * 16), \
            (__attribute__((address_space(3))) unsigned int*)(dW_ + t * 1024), 16, 0, 0); \
    }                                                                                 \
} while (0)

// 4 vector loads of the w0/b0 slice for kt (replaces the 4 A-loads)
#define LDW0(KT, WA, WB, BA, BB) do {                                                 \
    const int k0_ = (KT) * 32 + quad * 8;                                             \
    WA = *(const f32x4*)(w0f + k0_);                                                  \
    WB = *(const f32x4*)(w0f + k0_ + 4);                                              \
    BA = *(const f32x4*)(b0f + k0_);                                                  \
    BB = *(const f32x4*)(b0f + k0_ + 4);                                              \
} while (0)

// build hi/lo A fragments: identical arithmetic to the old layer0p
#define COMP0(WA, WB, BA, BB) do {                                                    \
    _Pragma("unroll")                                                                 \
    for (int mm = 0; mm < 2; ++mm) {                                                  \
        const float xm_ = mm ? x1 : x0;                                               \
        f16x8 h_, l_;                                                                 \
        _Pragma("unroll")                                                             \
        for (int j = 0; j < 4; ++j) {                                                 \
            float v_ = xm_ * WA[j] + BA[j];                                           \
            v_ = v_ > 0.f ? v_ : 0.f;                                                 \
            _Float16 hs_ = (_Float16)v_;                                              \
            h_[j] = hs_; l_[j] = (_Float16)(v_ - (float)hs_);                         \
        }                                                                             \
        _Pragma("unroll")                                                             \
        for (int j = 0; j < 4; ++j) {                                                 \
            float v_ = xm_ * WB[j] + BB[j];                                           \
            v_ = v_ > 0.f ? v_ : 0.f;                                                 \
            _Float16 hs_ = (_Float16)v_;                                              \
            h_[4 + j] = hs_; l_[4 + j] = (_Float16)(v_ - (float)hs_);                 \
        }                                                                             \
        cah[mm] = h_; cal[mm] = l_;                                                   \
    }                                                                                 \
} while (0)

#define LDB0(BUF, BF) do {                                                            \
    _Pragma("unroll")                                                                 \
    for (int nn = 0; nn < 8; ++nn) {                                                  \
        int r_ = nn * 16 + lidx;                                                      \
        BF[nn] = *(const f16x8*)(&Bs[BUF][r_ * 40 + quad * 8]);                       \
    }                                                                                 \
} while (0)

#define MFMA0(BF) do {                                                                \
    _Pragma("unroll")                                                                 \
    for (int mm = 0; mm < 2; ++mm)                                                    \
        _Pragma("unroll")                                                             \
        for (int nn = 0; nn < 8; ++nn) {                                              \
            acc[mm][nn] = __builtin_amdgcn_mfma_f32_16x16x32_f16(cah[mm], BF[nn], acc[mm][nn], 0, 0, 0); \
            acc[mm][nn] = __builtin_amdgcn_mfma_f32_16x16x32_f16(cal[mm], BF[nn], acc[mm][nn], 0, 0, 0); \
        }                                                                             \
} while (0)

#define GATE0() do {                                                                  \
    asm volatile("s_waitcnt vmcnt(4)" ::: "memory");                                  \
    __builtin_amdgcn_sched_barrier(0);                                                \
    __builtin_amdgcn_s_barrier();                                                     \
    __builtin_amdgcn_sched_barrier(0);                                                \
} while (0)

// SUPERF(s): W(2s) in A-set (landed), buffers pair P hold images 2s,2s+1.
#define SUPERF(S, P, DO_PF, DO_W2) do {                                               \
    f16x8 bfr0_[8];                                                                   \
    LDB0(2 * (P), bfr0_);                                                             \
    if (DO_PF) { PF0(2 * (S) + 2, 2 * ((P) ^ 1)); PF0(2 * (S) + 3, 2 * ((P) ^ 1) + 1); } \
    LDW0(2 * (S) + 1, wBa, wBb, bBa, bBb);                                            \
    COMP0(wAa, wAb, bAa, bAb);          /* A(2s) */                                   \
    MFMA0(bfr0_);                                                                     \
    f16x8 bfr1_[8];                                                                   \
    LDB0(2 * (P) + 1, bfr1_);                                                         \
    if (DO_W2) LDW0(2 * (S) + 2, wAa, wAb, bAa, bAb);                                 \
    COMP0(wBa, wBb, bBa, bBb);          /* A(2s+1) */                                 \
    MFMA0(bfr1_);                                                                     \
    GATE0();                                                                          \
} while (0)

    f16x8 cah[2], cal[2];
    f32x4 wAa, wAb, bAa, bAb, wBa, wBb, bBa, bBb;

    PF0(0, 0);
    PF0(1, 1);
    LDW0(0, wAa, wAb, bAa, bAb);
    __syncthreads();

    for (int ss = 0; ss < 15; ++ss) {
        SUPERF(2 * ss,     0, 1, 1);
        SUPERF(2 * ss + 1, 1, 1, 1);
    }
    SUPERF(30, 0, 1, 1);
    SUPERF(31, 1, 0, 0);

#undef SUPERF
#undef GATE0
#undef MFMA0
#undef LDB0
#undef COMP0
#undef LDW0
#undef PF0

    // epilogue: write h1 hi/lo pair in P-layout
    #pragma unroll
    for (int nn = 0; nn < 8; ++nn) {
        const int col = nt * 128 + nn * 16 + lidx;
        const float bv = bias[col];
        const int kt2 = col >> 5, quad2 = (col >> 3) & 3, j2 = col & 7;
        const size_t cb = ((size_t)(mt * 64 + kt2) << 12) + quad2 * 128 + j2;
        #pragma unroll
        for (int mm = 0; mm < 2; ++mm) {
            const int rowg = (mbase >> 4) + mm;
            #pragma unroll
            for (int r = 0; r < 4; ++r) {
                const int lidx2 = quad * 4 + r;
                float v = acc[mm][nn][r] + bv;
                v = v > 0.f ? v : 0.f;
                _Float16 hs = (_Float16)v;
                const size_t idx = cb + rowg * 512 + lidx2 * 8;
                Chg[idx] = hs;
                Clg[idx] = (_Float16)(v - (float)hs);
            }
        }
    }
}

// ---------------------------------------------------------------------------
// Fallback fp32 path (ws too small for packed images)
// ---------------------------------------------------------------------------
__global__ void layer0f(const float* __restrict__ xs, const float* __restrict__ w0,
                        const float* __restrict__ b0, float* __restrict__ A, int row0) {
    const int r = blockIdx.x;
    const int j = threadIdx.x * 8;
    const float x = (row0 + r < MPTS) ? xs[row0 + r] : 0.f;
    float* out = A + (size_t)r * HID + j;
    #pragma unroll
    for (int q = 0; q < 8; ++q) {
        float v = x * w0[j + q] + b0[j + q];
        out[q] = v > 0.f ? v : 0.f;
    }
}

__launch_bounds__(256)
__global__ void gemm_valu(const float* __restrict__ A, const float* __restrict__ W,
                          const float* __restrict__ bias, float* __restrict__ C) {
    __shared__ float As[16][132];
    __shared__ float Ws[16][132];
    const int tid = threadIdx.x;
    const int tx = tid & 15, ty = tid >> 4;
    const int n0 = blockIdx.x * 128;
    const int m0 = blockIdx.y * 128;
    const int am = tid & 127, ak = (tid >> 7) * 8;
    const int wn = (tid & 15) * 8, wk = tid >> 4;
    const float* aptr = A + (size_t)(m0 + am) * HID + ak;
    const float* wptr = W + (size_t)wk * HID + n0 + wn;
    float acc[8][8];
    #pragma unroll
    for (int i = 0; i < 8; ++i)
        #pragma unroll
        for (int j = 0; j < 8; ++j) acc[i][j] = 0.f;
    for (int k0 = 0; k0 < HID; k0 += 16) {
        f32x4 a0 = *(const f32x4*)(aptr + k0);
        f32x4 a1 = *(const f32x4*)(aptr + k0 + 4);
        f32x4 w0v = *(const f32x4*)(wptr + (size_t)k0 * HID);
        f32x4 w1v = *(const f32x4*)(wptr + (size_t)k0 * HID + 4);
        __syncthreads();
        As[ak + 0][am] = a0[0]; As[ak + 1][am] = a0[1];
        As[ak + 2][am] = a0[2]; As[ak + 3][am] = a0[3];
        As[ak + 4][am] = a1[0]; As[ak + 5][am] = a1[1];
        As[ak + 6][am] = a1[2]; As[ak + 7][am] = a1[3];
        *(f32x4*)&Ws[wk][wn]     = w0v;
        *(f32x4*)&Ws[wk][wn + 4] = w1v;
        __syncthreads();
        #pragma unroll
        for (int kk = 0; kk < 16; ++kk) {
            f32x4 av0 = *(const f32x4*)&As[kk][ty * 8];
            f32x4 av1 = *(const f32x4*)&As[kk][ty * 8 + 4];
            f32x4 bv0 = *(const f32x4*)&Ws[kk][tx * 8];
            f32x4 bv1 = *(const f32x4*)&Ws[kk][tx * 8 + 4];
            float a[8] = {av0[0], av0[1], av0[2], av0[3], av1[0], av1[1], av1[2], av1[3]};
            float b[8] = {bv0[0], bv0[1], bv0[2], bv0[3], bv1[0], bv1[1], bv1[2], bv1[3]};
            #pragma unroll
            for (int i = 0; i < 8; ++i)
                #pragma unroll
                for (int j = 0; j < 8; ++j) acc[i][j] += a[i] * b[j];
        }
    }
    #pragma unroll
    for (int i = 0; i < 8; ++i) {
        const int m = m0 + ty * 8 + i;
        #pragma unroll
        for (int jc = 0; jc < 2; ++jc) {
            const int n = n0 + tx * 8 + jc * 4;
            f32x4 v4;
            #pragma unroll
            for (int q = 0; q < 4; ++q) {
                float v = acc[i][jc * 4 + q] + bias[n + q];
                v4[q] = v > 0.f ? v : 0.f;
            }
            *(f32x4*)(C + (size_t)m * HID + n) = v4;
        }
    }
}

__global__ void layer4f(const float* __restrict__ A, const float* __restrict__ w4,
                        const float* __restrict__ b4, float* __restrict__ Amg, int row0) {
    const int lane = threadIdx.x & 63;
    const int wave = threadIdx.x >> 6;
    const int r    = blockIdx.x * 4 + wave;
    if (row0 + r >= MPTS) return;
    const float* ap = A + (size_t)r * HID;
    float s = 0.f;
    #pragma unroll
    for (int c = 0; c < 8; ++c) {
        const int col = c * 256 + lane * 4;
        f32x4 av = *(const f32x4*)(ap + col);
        f32x4 wv = *(const f32x4*)(w4 + col);
        s += av[0] * wv[0] + av[1] * wv[1] + av[2] * wv[2] + av[3] * wv[3];
    }
    #pragma unroll
    for (int off = 32; off; off >>= 1) s += __shfl_down(s, off);
    if (lane == 0) {
        float v = s + b4[0];
        Amg[row0 + r] = v > 0.f ? v : 0.f;
    }
}

// ---------------------------------------------------------------------------
// Fused multigrid cascade: all 5 levels in ONE kernel (r10-proven). Each
// block back-traces its 256-output dependency cone through LDS. Bitwise
// identical to the old 5x mg_level chain. b4p null => f = identity.
// ---------------------------------------------------------------------------
__global__ void mg_all(const float* __restrict__ Amg, float* __restrict__ outf,
                       const int* __restrict__ nbrs, const float* __restrict__ b4p) {
    __shared__ float Lb[16], L0[24], L1[40], L2[72], L3[136];
    const int t = threadIdx.x;
    const int NFIN = 524289;
    const int o0 = (int)blockIdx.x * 256;
    const float b4v = b4p ? b4p[0] : 0.f;
    const int stride = (nbrs[1] == 0 && nbrs[3] == 0 && nbrs[5] == 0) ? 2 : 1;

#define MGF(x) (b4p ? fmaxf((x) + b4v, 0.f) : (x))

    const int nin[5] = {16385, 32769, 65537, 131073, 262145};
    int OS4 = o0;
    int OC4 = (NFIN - o0 < 256) ? (NFIN - o0) : 256;
    int IS4 = (OS4 > 0) ? ((OS4 - 1) >> 1) : 0;
    int IE4 = ((OS4 + OC4) >> 1) + 1; if (IE4 > nin[4]) IE4 = nin[4];
    int OS3 = IS4, OC3 = IE4 - IS4;
    int IS3 = (OS3 > 0) ? ((OS3 - 1) >> 1) : 0;
    int IE3 = ((OS3 + OC3) >> 1) + 1; if (IE3 > nin[3]) IE3 = nin[3];
    int OS2 = IS3, OC2 = IE3 - IS3;
    int IS2 = (OS2 > 0) ? ((OS2 - 1) >> 1) : 0;
    int IE2 = ((OS2 + OC2) >> 1) + 1; if (IE2 > nin[2]) IE2 = nin[2];
    int OS1 = IS2, OC1 = IE2 - IS2;
    int IS1 = (OS1 > 0) ? ((OS1 - 1) >> 1) : 0;
    int IE1 = ((OS1 + OC1) >> 1) + 1; if (IE1 > nin[1]) IE1 = nin[1];
    int OS0 = IS1, OC0 = IE1 - IS1;
    int IS0 = (OS0 > 0) ? ((OS0 - 1) >> 1) : 0;
    int IE0 = ((OS0 + OC0) >> 1) + 1; if (IE0 > nin[0]) IE0 = nin[0];
    int BS = IS0, BC = IE0 - IS0;

    if (t < BC) Lb[t] = MGF(Amg[40 + BS + t]);
    __syncthreads();

#define MG_STAGE(LVL, INARR, INS, OUTARR, OS_, OC_) do {                              \
    if (t < (OC_)) {                                                                  \
        const int gj = (OS_) + t;                                                     \
        const int h = gj >> 1;                                                        \
        float v;                                                                      \
        if (gj & 1) v = 0.5f * (INARR[h - (INS)] + INARR[h + 1 - (INS)]);             \
        else        v = INARR[h - (INS)];                                             \
        _Pragma("unroll")                                                             \
        for (int t8 = 0; t8 < 8; ++t8) {                                              \
            const int idx = nbrs[((LVL) * 8 + t8) * stride];                          \
            if (idx == gj) v = MGF(Amg[8 * (4 - (LVL)) + t8]);                        \
        }                                                                             \
        OUTARR[t] = v;                                                                \
    }                                                                                 \
    __syncthreads();                                                                  \
} while (0)

    MG_STAGE(0, Lb, BS,  L0, OS0, OC0);
    MG_STAGE(1, L0, OS0, L1, OS1, OC1);
    MG_STAGE(2, L1, OS1, L2, OS2, OC2);
    MG_STAGE(3, L2, OS2, L3, OS3, OC3);

    if (t < OC4) {
        const int gj = OS4 + t;
        const int h = gj >> 1;
        float v;
        if (gj & 1) v = 0.5f * (L3[h - OS3] + L3[h + 1 - OS3]);
        else        v = L3[h - OS3];
        #pragma unroll
        for (int t8 = 0; t8 < 8; ++t8) {
            const int idx = nbrs[(4 * 8 + t8) * stride];
            if (idx == gj) v = MGF(Amg[t8]);
        }
        outf[gj] = v;
    }

#undef MG_STAGE
#undef MGF
}

// ---------------------------------------------------------------------------
extern "C" void kernel_launch(void* const* d_in, const int* in_sizes, int n_in,
                              void* d_out, int out_size, void* d_ws, size_t ws_size,
                              hipStream_t stream) {
    // ---- input order detection: dict (documented) / signature / alphabetical
    int iXS=0, iNB=1, iW0=4, iB0=5, iW1=6, iB1=7, iW2=8, iB2=9,
        iW3=10, iB3=11, iW4=12, iB4=13;                       // dict default
    if (n_in >= 14) {
        if (in_sizes[0] == HID) {
            iB0=0; iB1=1; iB2=2; iB3=3; iB4=4; iNB=7;
            iW0=8; iW1=9; iW2=10; iW3=11; iW4=12; iXS=13;
        } else if (!(in_sizes[1] == 40 || in_sizes[1] == 80)) {
            iXS=0; iW0=1; iB0=2; iW1=3; iB1=4; iW2=5; iB2=6;
            iW3=7; iB3=8; iW4=9; iB4=10; iNB=11;
        }
    }
    const float* xs = (const float*)d_in[iXS];
    const int* nbrs = (const int*)d_in[iNB];
    const float* w0 = (const float*)d_in[iW0];
    const float* b0 = (const float*)d_in[iB0];
    const float* w1 = (const float*)d_in[iW1];
    const float* b1 = (const float*)d_in[iB1];
    const float* w2 = (const float*)d_in[iW2];
    const float* b2 = (const float*)d_in[iB2];
    const float* w3 = (const float*)d_in[iW3];
    const float* b3 = (const float*)d_in[iB3];
    const float* w4 = (const float*)d_in[iW4];
    const float* b4 = (const float*)d_in[iB4];

    // ---- workspace layout ----
    char* ws = (char*)d_ws;
    const size_t szAmg = 66048;
    const size_t szAh1 = 524544;
    const size_t szAh2 = 1048832;
    float* Amg = (float*)(ws);
    float* ahA = (float*)(ws + szAmg);
    float* ahB = (float*)(ws + szAmg + szAh1);
    const size_t casc_end = szAmg + szAh1 + szAh2;       // 1,639,424
    const size_t szW    = (size_t)3 * 1024 * BIMG * 2;   // 31,457,280 (fp16)
    const size_t per_tile = 2ull * 128 * HID * 4;        // 2 MB (4 fp16 act bufs)

    const int use_mfma = (ws_size >= casc_end + szW + per_tile) ? 1 : 0;

    _Float16* wp = (_Float16*)(ws + casc_end);
    const size_t buf_start = use_mfma ? (casc_end + szW) : casc_end;

    size_t avail = ws_size - buf_start;
    int CT = (int)(avail / per_tile);
    if (CT < 1) CT = 1;
    if (CT > MTILES) CT = MTILES;   // single chunk when workspace allows

    if (use_mfma) {
        const size_t half = (size_t)CT * 128 * HID;       // f16 elems per buffer
        _Float16* bAh = (_Float16*)(ws + buf_start);
        _Float16* bAl = bAh + half;
        _Float16* bBh = bAh + 2 * half;
        _Float16* bBl = bAh + 3 * half;

        // fused layer-4 accumulates into Amg -> zero it (stream-ordered).
        hipMemsetAsync(Amg, 0, (size_t)MPTS * sizeof(float), stream);

        pack_w16<<<dim3(KTIL, NTIL, 3), 256, 0, stream>>>(w1, w2, w3, wp);

        for (int t0 = 0; t0 < MTILES; t0 += CT) {
            int tiles = (MTILES - t0 < CT) ? (MTILES - t0) : CT;
            int row0 = t0 * 128;
            dim3 ggrid(NTIL, tiles);
            // layer 0 fused with the xs->A0 rank-1 expansion (no layer0p)
            gemm_f0<<<ggrid, 256, 0, stream>>>(xs, w0, b0, wp, b1, bBh, bBl, row0);
            gemm_hl<<<ggrid, 256, 0, stream>>>(bBh, bBl, wp, b2, bAh, bAl, 1, 1,
                                               nullptr, nullptr, 0);
            // layer 2->3 gemm with fused layer-4 dot (no C write, no layer4p)
            gemm_hl<<<ggrid, 256, 0, stream>>>(bAh, bAl, wp, b3, bBh, bBl, 2, 0,
                                               Amg, w4, row0);
        }
    } else {
        float* bufA = (float*)(ws + buf_start);
        float* bufB = (float*)(ws + buf_start + (size_t)CT * 128 * HID * 4);
        for (int t0 = 0; t0 < MTILES; t0 += CT) {
            int tiles = (MTILES - t0 < CT) ? (MTILES - t0) : CT;
            int row0 = t0 * 128;
            layer0f<<<dim3(tiles * 128), 256, 0, stream>>>(xs, w0, b0, bufA, row0);
            dim3 ggrid(NTIL, tiles);
            gemm_valu<<<ggrid, 256, 0, stream>>>(bufA, w1, b1, bufB);
            gemm_valu<<<ggrid, 256, 0, stream>>>(bufB, w2, b2, bufA);
            gemm_valu<<<ggrid, 256, 0, stream>>>(bufA, w3, b3, bufB);
            layer4f<<<dim3(tiles * 32), 256, 0, stream>>>(bufB, w4, b4, Amg, row0);
        }
    }

    // fused multigrid cascade: one kernel for all 5 levels (final = 524289).
    const float* b4p = use_mfma ? b4 : nullptr;
    mg_all<<<dim3((524289 + 255) / 256), 256, 0, stream>>>(
        Amg, (float*)d_out, nbrs, b4p);
    (void)ahA; (void)ahB;
    (void)out_size;
}